// Round 1
// baseline (462.995 us; speedup 1.0000x reference)
//
#include <hip/hip_runtime.h>
#include <stdint.h>

#define SEQ 4096
#define EMB 2048
#define NH 16
#define HDIM 128

typedef _Float16 f16;
typedef _Float16 f16x2 __attribute__((ext_vector_type(2)));
typedef _Float16 f16x4 __attribute__((ext_vector_type(4)));
typedef _Float16 f16x8 __attribute__((ext_vector_type(8)));
typedef float f32x4 __attribute__((ext_vector_type(4)));

#define MFMA16(a, b, c) __builtin_amdgcn_mfma_f32_16x16x32_f16((a), (b), (c), 0, 0, 0)

// workspace layout (f16 element offsets)
#define OFF_XH   0ull          // 4096x2048 x in fp16; later reused as AO (attention out)
#define OFF_WCAT 8388608ull    // [3072][2048] = Wq | Wk | Wv
#define OFF_WHI  14680064ull   // Wo hi [2048][2048]
#define OFF_WLO  18874368ull   // Wo lo [2048][2048]
#define OFF_Q    23068672ull   // [4096][2048]
#define OFF_K    31457280ull   // [4096][512]
#define OFF_VT   33554432ull   // [512][4096]  (V transposed: Vt[hk*128+d][t])

__device__ __forceinline__ void gload16(const void* g, void* l) {
    __builtin_amdgcn_global_load_lds((const __attribute__((address_space(1))) unsigned int*)g,
                                     (__attribute__((address_space(3))) unsigned int*)l, 16, 0, 0);
}

// ---------------- fp32 -> fp16 conversion (+ Wo hi/lo split) ----------------
__global__ __launch_bounds__(256) void cvt_kernel(
    const float* __restrict__ x, const float* __restrict__ wq,
    const float* __restrict__ wk, const float* __restrict__ wv,
    const float* __restrict__ wo, f16* __restrict__ ws)
{
    int g = blockIdx.x * 256 + threadIdx.x;
    const float* src;
    size_t dst;
    int iswo = 0;
    if (g < 2097152)      { src = x  + (size_t)g * 4;                 dst = OFF_XH + (size_t)g * 4; }
    else if (g < 3145728) { int r = g - 2097152; src = wq + (size_t)r * 4; dst = OFF_WCAT + (size_t)r * 4; }
    else if (g < 3407872) { int r = g - 3145728; src = wk + (size_t)r * 4; dst = OFF_WCAT + 4194304ull + (size_t)r * 4; }
    else if (g < 3670016) { int r = g - 3407872; src = wv + (size_t)r * 4; dst = OFF_WCAT + 5242880ull + (size_t)r * 4; }
    else                  { int r = g - 3670016; src = wo + (size_t)r * 4; dst = OFF_WHI + (size_t)r * 4; iswo = 1; }
    float4 v = *(const float4*)src;
    f16x4 hi;
    hi[0] = (f16)v.x; hi[1] = (f16)v.y; hi[2] = (f16)v.z; hi[3] = (f16)v.w;
    *(f16x4*)&ws[dst] = hi;
    if (iswo) {
        f16x4 lo;
        lo[0] = (f16)(v.x - (float)hi[0]); lo[1] = (f16)(v.y - (float)hi[1]);
        lo[2] = (f16)(v.z - (float)hi[2]); lo[3] = (f16)(v.w - (float)hi[3]);
        *(f16x4*)&ws[dst + (OFF_WLO - OFF_WHI)] = lo;
    }
}

// ---------------- fused QKV projection GEMM ----------------
// C[m][n] = sum_k Xh[m][k] * Wcat[n][k];  n<2048 -> Q, n<2560 -> K, else -> V^T
__global__ __launch_bounds__(256) void qkv_gemm(
    const f16* __restrict__ Xh, const f16* __restrict__ Wcat,
    f16* __restrict__ Qb, f16* __restrict__ Kb, f16* __restrict__ Vt)
{
    __shared__ f16 As[128 * 32];
    __shared__ f16 Bs[128 * 32];
    const int tid = threadIdx.x;
    const int lane = tid & 63;
    const int w = tid >> 6;
    const int llo = lane & 15, lhi = lane >> 4;
    const int m0 = blockIdx.y * 128;
    const int n0 = blockIdx.x * 128;
    const int wr = (w >> 1) * 64, wc = (w & 1) * 64;

    f32x4 acc[4][4] = {};

    for (int k0 = 0; k0 < EMB; k0 += 32) {
#pragma unroll
        for (int i = 0; i < 2; ++i) {
            int c = tid + 256 * i;
            gload16(Xh + (size_t)(m0 + (c >> 2)) * EMB + k0 + (c & 3) * 8, &As[c * 8]);
        }
#pragma unroll
        for (int i = 0; i < 2; ++i) {
            int c = tid + 256 * i;
            gload16(Wcat + (size_t)(n0 + (c >> 2)) * EMB + k0 + (c & 3) * 8, &Bs[c * 8]);
        }
        __syncthreads();
        f16x8 af[4], bf[4];
#pragma unroll
        for (int mi = 0; mi < 4; ++mi) af[mi] = *(const f16x8*)&As[(wr + mi * 16 + llo) * 32 + lhi * 8];
#pragma unroll
        for (int ni = 0; ni < 4; ++ni) bf[ni] = *(const f16x8*)&Bs[(wc + ni * 16 + llo) * 32 + lhi * 8];
#pragma unroll
        for (int mi = 0; mi < 4; ++mi)
#pragma unroll
            for (int ni = 0; ni < 4; ++ni)
                acc[mi][ni] = MFMA16(af[mi], bf[ni], acc[mi][ni]);
        __syncthreads();
    }

    // epilogue: C/D layout col=lane&15, row=(lane>>4)*4+r
    if (n0 < 2048) {
#pragma unroll
        for (int mi = 0; mi < 4; ++mi) {
            int m = m0 + wr + mi * 16 + lhi * 4;
#pragma unroll
            for (int ni = 0; ni < 4; ++ni) {
                int n = n0 + wc + ni * 16 + llo;
#pragma unroll
                for (int r = 0; r < 4; ++r)
                    Qb[(size_t)(m + r) * EMB + n] = (f16)acc[mi][ni][r];
            }
        }
    } else if (n0 < 2560) {
#pragma unroll
        for (int mi = 0; mi < 4; ++mi) {
            int m = m0 + wr + mi * 16 + lhi * 4;
#pragma unroll
            for (int ni = 0; ni < 4; ++ni) {
                int n = n0 + wc + ni * 16 + llo - 2048;
#pragma unroll
                for (int r = 0; r < 4; ++r)
                    Kb[(size_t)(m + r) * 512 + n] = (f16)acc[mi][ni][r];
            }
        }
    } else {
#pragma unroll
        for (int mi = 0; mi < 4; ++mi) {
            int mb = m0 + wr + mi * 16 + lhi * 4;
#pragma unroll
            for (int ni = 0; ni < 4; ++ni) {
                int n = n0 + wc + ni * 16 + llo - 2560;
                f16x4 pv;
#pragma unroll
                for (int r = 0; r < 4; ++r) pv[r] = (f16)acc[mi][ni][r];
                *(f16x4*)&Vt[(size_t)n * SEQ + mb] = pv;
            }
        }
    }
}

// ---------------- flash attention (GQA), fp16 MFMA, swapped QK^T ----------------
__global__ __launch_bounds__(256, 2) void attn_kernel(
    const f16* __restrict__ Qb, const f16* __restrict__ Kb, const f16* __restrict__ Vt,
    f16* __restrict__ AO)
{
    __shared__ f16 Ks[2][32 * 128];   // K-tile [t=32][k=128], XOR-swizzled chunks
    __shared__ f16 Vs[2][128 * 32];   // V^T-tile [d=128][t=32], XOR-swizzled chunks
    const int tid = threadIdx.x, lane = tid & 63, w = tid >> 6;
    const int llo = lane & 15, lhi = lane >> 4;
    const int h = blockIdx.y, hk = h >> 2;
    const int wm0 = blockIdx.x * 128 + w * 32;
    const int hcol = h * HDIM;
    const float CS = 0.08838834764831845f * 1.4426950408889634f; // (1/sqrt(128))*log2(e)

    // Q fragments in registers (2 row-groups x 4 k-chunks)
    f16x8 qf[2][4];
#pragma unroll
    for (int G = 0; G < 2; ++G)
#pragma unroll
        for (int kk = 0; kk < 4; ++kk)
            qf[G][kk] = *(const f16x8*)&Qb[(size_t)(wm0 + G * 16 + llo) * EMB + hcol + kk * 32 + lhi * 8];

    float mrun[2] = { -3.0e38f, -3.0e38f };
    float lrun[2] = { 0.f, 0.f };
    f32x4 acc[2][8] = {};

    auto stage = [&](int buf, int t0) {
#pragma unroll
        for (int i = 0; i < 2; ++i) {           // K: 512 chunks of 16B, 16 chunks/row
            int c = tid + 256 * i;
            int row = c >> 4, sc = c & 15;
            int cc = sc ^ (row & 7);            // pre-swizzled source (LDS write is linear)
            gload16(Kb + (size_t)(t0 + row) * 512 + hk * HDIM + cc * 8, &Ks[buf][c * 8]);
        }
#pragma unroll
        for (int i = 0; i < 2; ++i) {           // V^T: 512 chunks, 4 chunks/row
            int c = tid + 256 * i;
            int row = c >> 2, sc = c & 3;
            int cc = sc ^ (row & 3);
            gload16(Vt + (size_t)(hk * HDIM + row) * SEQ + t0 + cc * 8, &Vs[buf][c * 8]);
        }
    };

    stage(0, 0);
    __syncthreads();

    for (int tt = 0; tt < 128; ++tt) {
        int cur = tt & 1;
        if (tt < 127) stage(cur ^ 1, (tt + 1) * 32);  // prefetch overlaps compute

        // QK^T swapped: s = K_tile * Q  ->  lane holds row m=llo, t=(16*hh + lhi*4 + r)
        f32x4 s[2][2] = {};
#pragma unroll
        for (int kk = 0; kk < 4; ++kk) {
            f16x8 kf0, kf1;
            { int row = llo;      int ccs = (kk * 4 + lhi) ^ (row & 7); kf0 = *(const f16x8*)&Ks[cur][row * 128 + ccs * 8]; }
            { int row = 16 + llo; int ccs = (kk * 4 + lhi) ^ (row & 7); kf1 = *(const f16x8*)&Ks[cur][row * 128 + ccs * 8]; }
            s[0][0] = MFMA16(kf0, qf[0][kk], s[0][0]);
            s[0][1] = MFMA16(kf1, qf[0][kk], s[0][1]);
            s[1][0] = MFMA16(kf0, qf[1][kk], s[1][0]);
            s[1][1] = MFMA16(kf1, qf[1][kk], s[1][1]);
        }

        // scale + tile max (mostly lane-local; rows live at m=llo)
        float tm[2];
#pragma unroll
        for (int G = 0; G < 2; ++G) {
            float t = -3.0e38f;
#pragma unroll
            for (int hh = 0; hh < 2; ++hh)
#pragma unroll
                for (int r = 0; r < 4; ++r) { float v = s[G][hh][r] * CS; s[G][hh][r] = v; t = fmaxf(t, v); }
            t = fmaxf(t, __shfl_xor(t, 16, 64));
            t = fmaxf(t, __shfl_xor(t, 32, 64));
            tm[G] = t;
        }
        // defer-max: skip rescale when no row got a new max anywhere in the wave
        int need = (tm[0] > mrun[0]) || (tm[1] > mrun[1]);
        if (__any(need)) {
#pragma unroll
            for (int G = 0; G < 2; ++G) {
                float mnew = fmaxf(mrun[G], tm[G]);
                float alpha = __builtin_amdgcn_exp2f(mrun[G] - mnew);
                mrun[G] = mnew; lrun[G] *= alpha;
                float ar[4];
#pragma unroll
                for (int r = 0; r < 4; ++r) ar[r] = __shfl(alpha, lhi * 4 + r, 64);
#pragma unroll
                for (int ni = 0; ni < 8; ++ni)
#pragma unroll
                    for (int r = 0; r < 4; ++r) acc[G][ni][r] *= ar[r];
            }
        }

        // exp, row-sum, pack P to fp16 pairs
        union F2U { f16x2 h; uint32_t u; };
        uint32_t pk[2][2][2];
#pragma unroll
        for (int G = 0; G < 2; ++G) {
            float ts = 0.f;
#pragma unroll
            for (int hh = 0; hh < 2; ++hh) {
#pragma unroll
                for (int r = 0; r < 4; ++r) { float p = __builtin_amdgcn_exp2f(s[G][hh][r] - mrun[G]); s[G][hh][r] = p; ts += p; }
                F2U a, b;
                a.h[0] = (f16)s[G][hh][0]; a.h[1] = (f16)s[G][hh][1];
                b.h[0] = (f16)s[G][hh][2]; b.h[1] = (f16)s[G][hh][3];
                pk[G][hh][0] = a.u; pk[G][hh][1] = b.u;
            }
            ts += __shfl_xor(ts, 16, 64);
            ts += __shfl_xor(ts, 32, 64);
            lrun[G] += ts;
        }

        // gather P into MFMA A-fragment layout: A[m=llo][t=lhi*8+j]
        f16x8 paf[2];
#pragma unroll
        for (int G = 0; G < 2; ++G) {
            union { f16x8 v; uint32_t u[4]; } pa;
#pragma unroll
            for (int jj = 0; jj < 4; ++jj) {
                int src = llo + 16 * ((2 * lhi + (jj >> 1)) & 3);
                uint32_t v0 = (uint32_t)__shfl((int)pk[G][0][jj & 1], src, 64);
                uint32_t v1 = (uint32_t)__shfl((int)pk[G][1][jj & 1], src, 64);
                pa.u[jj] = (lhi >= 2) ? v1 : v0;
            }
            paf[G] = pa.v;
        }

        // PV: out[m][d] += P * V   (B-frag from V^T tile, contiguous via swizzle)
#pragma unroll
        for (int ni = 0; ni < 8; ++ni) {
            int d = ni * 16 + llo;
            f16x8 vf = *(const f16x8*)&Vs[cur][d * 32 + ((lhi ^ (d & 3)) * 8)];
            acc[0][ni] = MFMA16(paf[0], vf, acc[0][ni]);
            acc[1][ni] = MFMA16(paf[1], vf, acc[1][ni]);
        }

        __syncthreads();  // drains prefetch (vmcnt 0) + barrier: next buffer ready
    }

    // finalize: divide by row sums, store merged-head fp16 [4096][2048]
#pragma unroll
    for (int G = 0; G < 2; ++G) {
        float linv = 1.0f / lrun[G];
        float lr[4];
#pragma unroll
        for (int r = 0; r < 4; ++r) lr[r] = __shfl(linv, lhi * 4 + r, 64);
#pragma unroll
        for (int ni = 0; ni < 8; ++ni) {
            int n = hcol + ni * 16 + llo;
#pragma unroll
            for (int r = 0; r < 4; ++r)
                AO[(size_t)(wm0 + G * 16 + lhi * 4 + r) * EMB + n] = (f16)(acc[G][ni][r] * lr[r]);
        }
    }
}

// ---------------- output projection: out = AO @ (Wo_hi + Wo_lo)^T, fp32 out ----------------
__global__ __launch_bounds__(256) void o_gemm(
    const f16* __restrict__ A, const f16* __restrict__ Whi, const f16* __restrict__ Wlo,
    float* __restrict__ Co)
{
    __shared__ f16 As[128 * 32];
    __shared__ f16 Bh[128 * 32];
    __shared__ f16 Bl[128 * 32];
    const int tid = threadIdx.x;
    const int lane = tid & 63;
    const int w = tid >> 6;
    const int llo = lane & 15, lhi = lane >> 4;
    const int m0 = blockIdx.y * 128;
    const int n0 = blockIdx.x * 128;
    const int wr = (w >> 1) * 64, wc = (w & 1) * 64;

    f32x4 acc[4][4] = {};

    for (int k0 = 0; k0 < EMB; k0 += 32) {
#pragma unroll
        for (int i = 0; i < 2; ++i) {
            int c = tid + 256 * i;
            gload16(A + (size_t)(m0 + (c >> 2)) * EMB + k0 + (c & 3) * 8, &As[c * 8]);
        }
#pragma unroll
        for (int i = 0; i < 2; ++i) {
            int c = tid + 256 * i;
            gload16(Whi + (size_t)(n0 + (c >> 2)) * EMB + k0 + (c & 3) * 8, &Bh[c * 8]);
        }
#pragma unroll
        for (int i = 0; i < 2; ++i) {
            int c = tid + 256 * i;
            gload16(Wlo + (size_t)(n0 + (c >> 2)) * EMB + k0 + (c & 3) * 8, &Bl[c * 8]);
        }
        __syncthreads();
        f16x8 af[4], bh[4], bl[4];
#pragma unroll
        for (int mi = 0; mi < 4; ++mi) af[mi] = *(const f16x8*)&As[(wr + mi * 16 + llo) * 32 + lhi * 8];
#pragma unroll
        for (int ni = 0; ni < 4; ++ni) bh[ni] = *(const f16x8*)&Bh[(wc + ni * 16 + llo) * 32 + lhi * 8];
#pragma unroll
        for (int ni = 0; ni < 4; ++ni) bl[ni] = *(const f16x8*)&Bl[(wc + ni * 16 + llo) * 32 + lhi * 8];
#pragma unroll
        for (int mi = 0; mi < 4; ++mi)
#pragma unroll
            for (int ni = 0; ni < 4; ++ni) {
                acc[mi][ni] = MFMA16(af[mi], bh[ni], acc[mi][ni]);
                acc[mi][ni] = MFMA16(af[mi], bl[ni], acc[mi][ni]);
            }
        __syncthreads();
    }

#pragma unroll
    for (int mi = 0; mi < 4; ++mi) {
        int m = m0 + wr + mi * 16 + lhi * 4;
#pragma unroll
        for (int ni = 0; ni < 4; ++ni) {
            int n = n0 + wc + ni * 16 + llo;
#pragma unroll
            for (int r = 0; r < 4; ++r)
                Co[(size_t)(m + r) * EMB + n] = acc[mi][ni][r];
        }
    }
}

extern "C" void kernel_launch(void* const* d_in, const int* in_sizes, int n_in,
                              void* d_out, int out_size, void* d_ws, size_t ws_size,
                              hipStream_t stream) {
    const float* x  = (const float*)d_in[0];
    const float* wq = (const float*)d_in[1];
    const float* wk = (const float*)d_in[2];
    const float* wv = (const float*)d_in[3];
    const float* wo = (const float*)d_in[4];
    f16* ws = (f16*)d_ws;

    f16* Xh   = ws + OFF_XH;     // also AO after attention
    f16* Wcat = ws + OFF_WCAT;
    f16* Whi  = ws + OFF_WHI;
    f16* Wlo  = ws + OFF_WLO;
    f16* Qb   = ws + OFF_Q;
    f16* Kb   = ws + OFF_K;
    f16* Vt   = ws + OFF_VT;

    cvt_kernel<<<18432, 256, 0, stream>>>(x, wq, wk, wv, wo, ws);
    qkv_gemm<<<dim3(24, 32), 256, 0, stream>>>(Xh, Wcat, Qb, Kb, Vt);
    attn_kernel<<<dim3(32, 16), 256, 0, stream>>>(Qb, Kb, Vt, Xh /*AO*/);
    o_gemm<<<dim3(16, 32), 256, 0, stream>>>(Xh /*AO*/, Whi, Wlo, (float*)d_out);
}

// Round 2
// 430.913 us; speedup vs baseline: 1.0745x; 1.0745x over previous
//
#include <hip/hip_runtime.h>
#include <stdint.h>

#define SEQ 4096
#define EMB 2048
#define NH 16
#define HDIM 128

typedef _Float16 f16;
typedef _Float16 f16x2 __attribute__((ext_vector_type(2)));
typedef _Float16 f16x4 __attribute__((ext_vector_type(4)));
typedef _Float16 f16x8 __attribute__((ext_vector_type(8)));
typedef float f32x4 __attribute__((ext_vector_type(4)));
typedef unsigned u32x2 __attribute__((ext_vector_type(2)));

#define MFMA16(a, b, c) __builtin_amdgcn_mfma_f32_16x16x32_f16((a), (b), (c), 0, 0, 0)

// workspace layout (f16 element offsets)
#define OFF_XH   0ull          // 4096x2048 x in fp16; later reused as AO (attention out)
#define OFF_WCAT 8388608ull    // [3072][2048] = Wq | Wk | Wv
#define OFF_WHI  14680064ull   // Wo hi [2048][2048]
#define OFF_WLO  18874368ull   // Wo lo [2048][2048]
#define OFF_Q    23068672ull   // [4096][2048]
#define OFF_K    31457280ull   // [4096][512]
#define OFF_VT   33554432ull   // [512][4096]  (V transposed: Vt[hk*128+d][t])

__device__ __forceinline__ void gload16(const void* g, void* l) {
    __builtin_amdgcn_global_load_lds((const __attribute__((address_space(1))) unsigned int*)g,
                                     (__attribute__((address_space(3))) unsigned int*)l, 16, 0, 0);
}

// --- lane-pair swaps (permlane on gfx950; shfl fallback keeps compile safe) ---
__device__ __forceinline__ void swap32p(uint32_t& x, uint32_t& y) {
#if __has_builtin(__builtin_amdgcn_permlane32_swap)
    u32x2 r = __builtin_amdgcn_permlane32_swap(x, y, false, false);
    x = r[0]; y = r[1];
#else
    int l = __lane_id();
    uint32_t xs = (uint32_t)__shfl_xor((int)x, 32, 64), ys = (uint32_t)__shfl_xor((int)y, 32, 64);
    uint32_t nx = (l < 32) ? x : ys;
    uint32_t ny = (l < 32) ? xs : y;
    x = nx; y = ny;
#endif
}
__device__ __forceinline__ void swap16p(uint32_t& x, uint32_t& y) {
#if __has_builtin(__builtin_amdgcn_permlane16_swap)
    u32x2 r = __builtin_amdgcn_permlane16_swap(x, y, false, false);
    x = r[0]; y = r[1];
#else
    int l = __lane_id();
    uint32_t xs = (uint32_t)__shfl_xor((int)x, 16, 64), ys = (uint32_t)__shfl_xor((int)y, 16, 64);
    uint32_t nx = (l & 16) ? ys : x;
    uint32_t ny = (l & 16) ? y : xs;
    x = nx; y = ny;
#endif
}
__device__ __forceinline__ float red_max_lhi(float t) {
    uint32_t a = __float_as_uint(t), b = a;
    swap16p(a, b);
    t = fmaxf(__uint_as_float(a), __uint_as_float(b));
    a = __float_as_uint(t); b = a;
    swap32p(a, b);
    return fmaxf(__uint_as_float(a), __uint_as_float(b));
}
__device__ __forceinline__ float red_sum_lhi(float t) {
    uint32_t a = __float_as_uint(t), b = a;
    swap16p(a, b);
    t = __uint_as_float(a) + __uint_as_float(b);
    a = __float_as_uint(t); b = a;
    swap32p(a, b);
    return __uint_as_float(a) + __uint_as_float(b);
}

// ---------------- fp32 -> fp16 conversion (+ Wo hi/lo split) ----------------
__global__ __launch_bounds__(256) void cvt_kernel(
    const float* __restrict__ x, const float* __restrict__ wq,
    const float* __restrict__ wk, const float* __restrict__ wv,
    const float* __restrict__ wo, f16* __restrict__ ws)
{
    int g = blockIdx.x * 256 + threadIdx.x;
    const float* src;
    size_t dst;
    int iswo = 0;
    if (g < 2097152)      { src = x  + (size_t)g * 4;                 dst = OFF_XH + (size_t)g * 4; }
    else if (g < 3145728) { int r = g - 2097152; src = wq + (size_t)r * 4; dst = OFF_WCAT + (size_t)r * 4; }
    else if (g < 3407872) { int r = g - 3145728; src = wk + (size_t)r * 4; dst = OFF_WCAT + 4194304ull + (size_t)r * 4; }
    else if (g < 3670016) { int r = g - 3407872; src = wv + (size_t)r * 4; dst = OFF_WCAT + 5242880ull + (size_t)r * 4; }
    else                  { int r = g - 3670016; src = wo + (size_t)r * 4; dst = OFF_WHI + (size_t)r * 4; iswo = 1; }
    float4 v = *(const float4*)src;
    f16x4 hi;
    hi[0] = (f16)v.x; hi[1] = (f16)v.y; hi[2] = (f16)v.z; hi[3] = (f16)v.w;
    *(f16x4*)&ws[dst] = hi;
    if (iswo) {
        f16x4 lo;
        lo[0] = (f16)(v.x - (float)hi[0]); lo[1] = (f16)(v.y - (float)hi[1]);
        lo[2] = (f16)(v.z - (float)hi[2]); lo[3] = (f16)(v.w - (float)hi[3]);
        *(f16x4*)&ws[dst + (OFF_WLO - OFF_WHI)] = lo;
    }
}

// ---------------- fused QKV projection GEMM ----------------
__global__ __launch_bounds__(256) void qkv_gemm(
    const f16* __restrict__ Xh, const f16* __restrict__ Wcat,
    f16* __restrict__ Qb, f16* __restrict__ Kb, f16* __restrict__ Vt)
{
    __shared__ f16 As[128 * 32];
    __shared__ f16 Bs[128 * 32];
    const int tid = threadIdx.x;
    const int lane = tid & 63;
    const int w = tid >> 6;
    const int llo = lane & 15, lhi = lane >> 4;
    const int m0 = blockIdx.y * 128;
    const int n0 = blockIdx.x * 128;
    const int wr = (w >> 1) * 64, wc = (w & 1) * 64;

    f32x4 acc[4][4] = {};

    for (int k0 = 0; k0 < EMB; k0 += 32) {
#pragma unroll
        for (int i = 0; i < 2; ++i) {
            int c = tid + 256 * i;
            gload16(Xh + (size_t)(m0 + (c >> 2)) * EMB + k0 + (c & 3) * 8, &As[c * 8]);
        }
#pragma unroll
        for (int i = 0; i < 2; ++i) {
            int c = tid + 256 * i;
            gload16(Wcat + (size_t)(n0 + (c >> 2)) * EMB + k0 + (c & 3) * 8, &Bs[c * 8]);
        }
        __syncthreads();
        f16x8 af[4], bf[4];
#pragma unroll
        for (int mi = 0; mi < 4; ++mi) af[mi] = *(const f16x8*)&As[(wr + mi * 16 + llo) * 32 + lhi * 8];
#pragma unroll
        for (int ni = 0; ni < 4; ++ni) bf[ni] = *(const f16x8*)&Bs[(wc + ni * 16 + llo) * 32 + lhi * 8];
#pragma unroll
        for (int mi = 0; mi < 4; ++mi)
#pragma unroll
            for (int ni = 0; ni < 4; ++ni)
                acc[mi][ni] = MFMA16(af[mi], bf[ni], acc[mi][ni]);
        __syncthreads();
    }

    if (n0 < 2048) {
#pragma unroll
        for (int mi = 0; mi < 4; ++mi) {
            int m = m0 + wr + mi * 16 + lhi * 4;
#pragma unroll
            for (int ni = 0; ni < 4; ++ni) {
                int n = n0 + wc + ni * 16 + llo;
#pragma unroll
                for (int r = 0; r < 4; ++r)
                    Qb[(size_t)(m + r) * EMB + n] = (f16)acc[mi][ni][r];
            }
        }
    } else if (n0 < 2560) {
#pragma unroll
        for (int mi = 0; mi < 4; ++mi) {
            int m = m0 + wr + mi * 16 + lhi * 4;
#pragma unroll
            for (int ni = 0; ni < 4; ++ni) {
                int n = n0 + wc + ni * 16 + llo - 2048;
#pragma unroll
                for (int r = 0; r < 4; ++r)
                    Kb[(size_t)(m + r) * 512 + n] = (f16)acc[mi][ni][r];
            }
        }
    } else {
#pragma unroll
        for (int mi = 0; mi < 4; ++mi) {
            int mb = m0 + wr + mi * 16 + lhi * 4;
#pragma unroll
            for (int ni = 0; ni < 4; ++ni) {
                int n = n0 + wc + ni * 16 + llo - 2560;
                f16x4 pv;
#pragma unroll
                for (int r = 0; r < 4; ++r) pv[r] = (f16)acc[mi][ni][r];
                *(f16x4*)&Vt[(size_t)n * SEQ + mb] = pv;
            }
        }
    }
}

// ---------------- flash attention (GQA), fp16 MFMA, swapped QK^T, KV tile 64 ----------------
__global__ __launch_bounds__(256, 2) void attn_kernel(
    const f16* __restrict__ Qb, const f16* __restrict__ Kb, const f16* __restrict__ Vt,
    f16* __restrict__ AO)
{
    __shared__ f16 Ks[2][64 * 128];   // K-tile [t=64][k=128], chunk pos = logical ^ (row&7)
    __shared__ f16 Vs[2][128 * 64];   // V^T-tile [d=128][t=64], chunk pos = logical ^ (row&7)
    const int tid = threadIdx.x, lane = tid & 63, w = tid >> 6;
    const int llo = lane & 15, lhi = lane >> 4;
    const int h = blockIdx.y, hk = h >> 2;
    const int wm0 = blockIdx.x * 128 + w * 32;
    const int hcol = h * HDIM;
    const float CS = 0.08838834764831845f * 1.4426950408889634f; // (1/sqrt(128))*log2(e)

    // Q fragments in registers (2 row-groups x 4 k-chunks)
    f16x8 qf[2][4];
#pragma unroll
    for (int G = 0; G < 2; ++G)
#pragma unroll
        for (int kk = 0; kk < 4; ++kk)
            qf[G][kk] = *(const f16x8*)&Qb[(size_t)(wm0 + G * 16 + llo) * EMB + hcol + kk * 32 + lhi * 8];

    // hoisted staging source pointers (advance by uniform t0 per tile)
    const f16* kgp[4];
    const f16* vgp[4];
#pragma unroll
    for (int i = 0; i < 4; ++i) {
        int c = tid + 256 * i;
        int row = c >> 4, cc = (c & 15) ^ (row & 7);
        kgp[i] = Kb + (size_t)row * 512 + hk * HDIM + cc * 8;
    }
#pragma unroll
    for (int i = 0; i < 4; ++i) {
        int c = tid + 256 * i;
        int row = c >> 3, cc = (c & 7) ^ (row & 7);
        vgp[i] = Vt + (size_t)(hk * HDIM + row) * SEQ + cc * 8;
    }

    float mrun[2] = { -3.0e38f, -3.0e38f };
    float lrun[2] = { 0.f, 0.f };
    f32x4 acc[2][8] = {};

    auto stage = [&](int buf, int t0) {
#pragma unroll
        for (int i = 0; i < 4; ++i)
            gload16(kgp[i] + (size_t)t0 * 512, &Ks[buf][(tid + 256 * i) * 8]);
#pragma unroll
        for (int i = 0; i < 4; ++i)
            gload16(vgp[i] + t0, &Vs[buf][(tid + 256 * i) * 8]);
    };

    stage(0, 0);
    __syncthreads();

    for (int tt = 0; tt < 64; ++tt) {
        int cur = tt & 1;
        if (tt < 63) stage(cur ^ 1, (tt + 1) * 64);  // prefetch overlaps compute

        // QK^T swapped: s = K_tile * Q -> lane holds q-row m=llo, t = 16*hh + lhi*4 + r
        f32x4 s[2][4] = {};
        __builtin_amdgcn_s_setprio(1);
#pragma unroll
        for (int kk = 0; kk < 4; ++kk) {
            f16x8 kf[4];
#pragma unroll
            for (int hh = 0; hh < 4; ++hh) {
                int row = llo + 16 * hh;
                int ccs = (kk * 4 + lhi) ^ (row & 7);
                kf[hh] = *(const f16x8*)&Ks[cur][row * 128 + ccs * 8];
            }
#pragma unroll
            for (int hh = 0; hh < 4; ++hh) {
                s[0][hh] = MFMA16(kf[hh], qf[0][kk], s[0][hh]);
                s[1][hh] = MFMA16(kf[hh], qf[1][kk], s[1][hh]);
            }
        }
        __builtin_amdgcn_s_setprio(0);

        // scale + tile max (rows live at m=llo; reduce across lhi via permlane)
        float tm[2];
#pragma unroll
        for (int G = 0; G < 2; ++G) {
            float t = -3.0e38f;
#pragma unroll
            for (int hh = 0; hh < 4; ++hh)
#pragma unroll
                for (int r = 0; r < 4; ++r) { float v = s[G][hh][r] * CS; s[G][hh][r] = v; t = fmaxf(t, v); }
            tm[G] = red_max_lhi(t);
        }
        int need = (tm[0] > mrun[0]) || (tm[1] > mrun[1]);
        if (__any(need)) {
#pragma unroll
            for (int G = 0; G < 2; ++G) {
                float mnew = fmaxf(mrun[G], tm[G]);
                float alpha = __builtin_amdgcn_exp2f(mrun[G] - mnew);
                mrun[G] = mnew; lrun[G] *= alpha;
                float ar[4];
#pragma unroll
                for (int r = 0; r < 4; ++r) ar[r] = __shfl(alpha, lhi * 4 + r, 64);
#pragma unroll
                for (int ni = 0; ni < 8; ++ni)
#pragma unroll
                    for (int r = 0; r < 4; ++r) acc[G][ni][r] *= ar[r];
            }
        }

        // exp, row-sum, pack P to fp16 dwords Y[G][hh][jj]
        union F2U { f16x2 h; uint32_t u; };
        uint32_t Y[2][4][2];
#pragma unroll
        for (int G = 0; G < 2; ++G) {
            float ts = 0.f;
#pragma unroll
            for (int hh = 0; hh < 4; ++hh) {
#pragma unroll
                for (int r = 0; r < 4; ++r) { float p = __builtin_amdgcn_exp2f(s[G][hh][r] - mrun[G]); s[G][hh][r] = p; ts += p; }
                F2U a, b;
                a.h[0] = (f16)s[G][hh][0]; a.h[1] = (f16)s[G][hh][1];
                b.h[0] = (f16)s[G][hh][2]; b.h[1] = (f16)s[G][hh][3];
                Y[G][hh][0] = a.u; Y[G][hh][1] = b.u;
            }
            lrun[G] += red_sum_lhi(ts);
        }

        // gather P into A-frag [m=llo][t = 32c + 8*lhi + j] via permlane swaps
        f16x8 paf[2][2];
#pragma unroll
        for (int G = 0; G < 2; ++G)
#pragma unroll
            for (int c = 0; c < 2; ++c) {
                union { f16x8 v; uint32_t u[4]; } pa;
#pragma unroll
                for (int jj = 0; jj < 2; ++jj) {
                    uint32_t xa = Y[G][2 * c][jj], xb = Y[G][2 * c + 1][jj];
                    swap32p(xa, xb);
                    swap16p(xa, xb);
                    pa.u[jj] = xa; pa.u[2 + jj] = xb;
                }
                paf[G][c] = pa.v;
            }

        // PV: out[m][d] += P * V  (V^T rows are t-contiguous; pos swizzled by d&7)
        __builtin_amdgcn_s_setprio(1);
#pragma unroll
        for (int c = 0; c < 2; ++c)
#pragma unroll
            for (int ni = 0; ni < 8; ++ni) {
                int d = ni * 16 + llo;
                f16x8 vf = *(const f16x8*)&Vs[cur][d * 64 + (((4 * c + lhi) ^ (d & 7)) * 8)];
                acc[0][ni] = MFMA16(paf[0][c], vf, acc[0][ni]);
                acc[1][ni] = MFMA16(paf[1][c], vf, acc[1][ni]);
            }
        __builtin_amdgcn_s_setprio(0);

        __syncthreads();  // drains prefetch (vmcnt 0) + barrier: next buffer ready
    }

    // finalize: divide by row sums, store merged-head fp16 [4096][2048]
#pragma unroll
    for (int G = 0; G < 2; ++G) {
        float linv = 1.0f / lrun[G];
        float lr[4];
#pragma unroll
        for (int r = 0; r < 4; ++r) lr[r] = __shfl(linv, lhi * 4 + r, 64);
#pragma unroll
        for (int ni = 0; ni < 8; ++ni) {
            int n = hcol + ni * 16 + llo;
#pragma unroll
            for (int r = 0; r < 4; ++r)
                AO[(size_t)(wm0 + G * 16 + lhi * 4 + r) * EMB + n] = (f16)(acc[G][ni][r] * lr[r]);
        }
    }
}

// ---------------- output projection: out = AO @ (Wo_hi + Wo_lo)^T, fp32 out ----------------
__global__ __launch_bounds__(256) void o_gemm(
    const f16* __restrict__ A, const f16* __restrict__ Whi, const f16* __restrict__ Wlo,
    float* __restrict__ Co)
{
    __shared__ f16 As[128 * 32];
    __shared__ f16 Bh[128 * 32];
    __shared__ f16 Bl[128 * 32];
    const int tid = threadIdx.x;
    const int lane = tid & 63;
    const int w = tid >> 6;
    const int llo = lane & 15, lhi = lane >> 4;
    const int m0 = blockIdx.y * 128;
    const int n0 = blockIdx.x * 128;
    const int wr = (w >> 1) * 64, wc = (w & 1) * 64;

    f32x4 acc[4][4] = {};

    for (int k0 = 0; k0 < EMB; k0 += 32) {
#pragma unroll
        for (int i = 0; i < 2; ++i) {
            int c = tid + 256 * i;
            gload16(A + (size_t)(m0 + (c >> 2)) * EMB + k0 + (c & 3) * 8, &As[c * 8]);
        }
#pragma unroll
        for (int i = 0; i < 2; ++i) {
            int c = tid + 256 * i;
            gload16(Whi + (size_t)(n0 + (c >> 2)) * EMB + k0 + (c & 3) * 8, &Bh[c * 8]);
        }
#pragma unroll
        for (int i = 0; i < 2; ++i) {
            int c = tid + 256 * i;
            gload16(Wlo + (size_t)(n0 + (c >> 2)) * EMB + k0 + (c & 3) * 8, &Bl[c * 8]);
        }
        __syncthreads();
        f16x8 af[4], bh[4], bl[4];
#pragma unroll
        for (int mi = 0; mi < 4; ++mi) af[mi] = *(const f16x8*)&As[(wr + mi * 16 + llo) * 32 + lhi * 8];
#pragma unroll
        for (int ni = 0; ni < 4; ++ni) bh[ni] = *(const f16x8*)&Bh[(wc + ni * 16 + llo) * 32 + lhi * 8];
#pragma unroll
        for (int ni = 0; ni < 4; ++ni) bl[ni] = *(const f16x8*)&Bl[(wc + ni * 16 + llo) * 32 + lhi * 8];
#pragma unroll
        for (int mi = 0; mi < 4; ++mi)
#pragma unroll
            for (int ni = 0; ni < 4; ++ni) {
                acc[mi][ni] = MFMA16(af[mi], bh[ni], acc[mi][ni]);
                acc[mi][ni] = MFMA16(af[mi], bl[ni], acc[mi][ni]);
            }
        __syncthreads();
    }

#pragma unroll
    for (int mi = 0; mi < 4; ++mi) {
        int m = m0 + wr + mi * 16 + lhi * 4;
#pragma unroll
        for (int ni = 0; ni < 4; ++ni) {
            int n = n0 + wc + ni * 16 + llo;
#pragma unroll
            for (int r = 0; r < 4; ++r)
                Co[(size_t)(m + r) * EMB + n] = acc[mi][ni][r];
        }
    }
}

extern "C" void kernel_launch(void* const* d_in, const int* in_sizes, int n_in,
                              void* d_out, int out_size, void* d_ws, size_t ws_size,
                              hipStream_t stream) {
    const float* x  = (const float*)d_in[0];
    const float* wq = (const float*)d_in[1];
    const float* wk = (const float*)d_in[2];
    const float* wv = (const float*)d_in[3];
    const float* wo = (const float*)d_in[4];
    f16* ws = (f16*)d_ws;

    f16* Xh   = ws + OFF_XH;     // also AO after attention
    f16* Wcat = ws + OFF_WCAT;
    f16* Whi  = ws + OFF_WHI;
    f16* Wlo  = ws + OFF_WLO;
    f16* Qb   = ws + OFF_Q;
    f16* Kb   = ws + OFF_K;
    f16* Vt   = ws + OFF_VT;

    cvt_kernel<<<18432, 256, 0, stream>>>(x, wq, wk, wv, wo, ws);
    qkv_gemm<<<dim3(24, 32), 256, 0, stream>>>(Xh, Wcat, Qb, Kb, Vt);
    attn_kernel<<<dim3(32, 16), 256, 0, stream>>>(Qb, Kb, Vt, Xh /*AO*/);
    o_gemm<<<dim3(16, 32), 256, 0, stream>>>(Xh /*AO*/, Whi, Wlo, (float*)d_out);
}

// Round 4
// 385.616 us; speedup vs baseline: 1.2007x; 1.1175x over previous
//
#include <hip/hip_runtime.h>
#include <stdint.h>

#define SEQ 4096
#define EMB 2048
#define NH 16
#define HDIM 128

typedef _Float16 f16;
typedef _Float16 f16x2 __attribute__((ext_vector_type(2)));
typedef _Float16 f16x4 __attribute__((ext_vector_type(4)));
typedef _Float16 f16x8 __attribute__((ext_vector_type(8)));
typedef float f32x4 __attribute__((ext_vector_type(4)));
typedef unsigned u32x2 __attribute__((ext_vector_type(2)));

#define MFMA16(a, b, c) __builtin_amdgcn_mfma_f32_16x16x32_f16((a), (b), (c), 0, 0, 0)

// workspace layout (f16 element offsets)
#define OFF_XH   0ull          // 4096x2048 x in fp16; later reused as AO (attention out)
#define OFF_WCAT 8388608ull    // [3072][2048] = Wq | Wk | Wv
#define OFF_WO   14680064ull   // Wo fp16 [2048][2048]
#define OFF_Q    23068672ull   // [4096][2048]  (pre-scaled by 1/sqrt(D)*log2e)
#define OFF_K    31457280ull   // [4096][512]
#define OFF_VT   33554432ull   // [512][4096]  (V transposed: Vt[hk*128+d][t])

__device__ __forceinline__ void gload16(const void* g, void* l) {
    __builtin_amdgcn_global_load_lds((const __attribute__((address_space(1))) unsigned int*)g,
                                     (__attribute__((address_space(3))) unsigned int*)l, 16, 0, 0);
}

// --- lane-pair swaps (permlane on gfx950; shfl fallback keeps compile safe) ---
__device__ __forceinline__ void swap32p(uint32_t& x, uint32_t& y) {
#if __has_builtin(__builtin_amdgcn_permlane32_swap)
    u32x2 r = __builtin_amdgcn_permlane32_swap(x, y, false, false);
    x = r[0]; y = r[1];
#else
    int l = __lane_id();
    uint32_t xs = (uint32_t)__shfl_xor((int)x, 32, 64), ys = (uint32_t)__shfl_xor((int)y, 32, 64);
    uint32_t nx = (l < 32) ? x : ys;
    uint32_t ny = (l < 32) ? xs : y;
    x = nx; y = ny;
#endif
}
__device__ __forceinline__ void swap16p(uint32_t& x, uint32_t& y) {
#if __has_builtin(__builtin_amdgcn_permlane16_swap)
    u32x2 r = __builtin_amdgcn_permlane16_swap(x, y, false, false);
    x = r[0]; y = r[1];
#else
    int l = __lane_id();
    uint32_t xs = (uint32_t)__shfl_xor((int)x, 16, 64), ys = (uint32_t)__shfl_xor((int)y, 16, 64);
    uint32_t nx = (l & 16) ? ys : x;
    uint32_t ny = (l & 16) ? y : xs;
    x = nx; y = ny;
#endif
}
__device__ __forceinline__ float red_max_lhi(float t) {
    uint32_t a = __float_as_uint(t), b = a;
    swap16p(a, b);
    t = fmaxf(__uint_as_float(a), __uint_as_float(b));
    a = __float_as_uint(t); b = a;
    swap32p(a, b);
    return fmaxf(__uint_as_float(a), __uint_as_float(b));
}
__device__ __forceinline__ float red_sum_lhi(float t) {
    uint32_t a = __float_as_uint(t), b = a;
    swap16p(a, b);
    t = __uint_as_float(a) + __uint_as_float(b);
    a = __float_as_uint(t); b = a;
    swap32p(a, b);
    return __uint_as_float(a) + __uint_as_float(b);
}

// ---------------- fp32 -> fp16 conversion ----------------
__global__ __launch_bounds__(256) void cvt_kernel(
    const float* __restrict__ x, const float* __restrict__ wq,
    const float* __restrict__ wk, const float* __restrict__ wv,
    const float* __restrict__ wo, f16* __restrict__ ws)
{
    int g = blockIdx.x * 256 + threadIdx.x;
    const float* src;
    size_t dst;
    if (g < 2097152)      { src = x  + (size_t)g * 4;                 dst = OFF_XH + (size_t)g * 4; }
    else if (g < 3145728) { int r = g - 2097152; src = wq + (size_t)r * 4; dst = OFF_WCAT + (size_t)r * 4; }
    else if (g < 3407872) { int r = g - 3145728; src = wk + (size_t)r * 4; dst = OFF_WCAT + 4194304ull + (size_t)r * 4; }
    else if (g < 3670016) { int r = g - 3407872; src = wv + (size_t)r * 4; dst = OFF_WCAT + 5242880ull + (size_t)r * 4; }
    else                  { int r = g - 3670016; src = wo + (size_t)r * 4; dst = OFF_WO + (size_t)r * 4; }
    float4 v = *(const float4*)src;
    f16x4 hv;
    hv[0] = (f16)v.x; hv[1] = (f16)v.y; hv[2] = (f16)v.z; hv[3] = (f16)v.w;
    *(f16x4*)&ws[dst] = hv;
}

// ---------------- fused QKV projection GEMM ----------------
__global__ __launch_bounds__(256) void qkv_gemm(
    const f16* __restrict__ Xh, const f16* __restrict__ Wcat,
    f16* __restrict__ Qb, f16* __restrict__ Kb, f16* __restrict__ Vt)
{
    __shared__ f16 As[128 * 32];
    __shared__ f16 Bs[128 * 32];
    const int tid = threadIdx.x;
    const int lane = tid & 63;
    const int w = tid >> 6;
    const int llo = lane & 15, lhi = lane >> 4;
    const int m0 = blockIdx.y * 128;
    const int n0 = blockIdx.x * 128;
    const int wr = (w >> 1) * 64, wc = (w & 1) * 64;
    const float CS = 0.08838834764831845f * 1.4426950408889634f; // (1/sqrt(128))*log2(e)

    f32x4 acc[4][4] = {};

    for (int k0 = 0; k0 < EMB; k0 += 32) {
#pragma unroll
        for (int i = 0; i < 2; ++i) {
            int c = tid + 256 * i;
            gload16(Xh + (size_t)(m0 + (c >> 2)) * EMB + k0 + (c & 3) * 8, &As[c * 8]);
        }
#pragma unroll
        for (int i = 0; i < 2; ++i) {
            int c = tid + 256 * i;
            gload16(Wcat + (size_t)(n0 + (c >> 2)) * EMB + k0 + (c & 3) * 8, &Bs[c * 8]);
        }
        __syncthreads();
        f16x8 af[4], bf[4];
#pragma unroll
        for (int mi = 0; mi < 4; ++mi) af[mi] = *(const f16x8*)&As[(wr + mi * 16 + llo) * 32 + lhi * 8];
#pragma unroll
        for (int ni = 0; ni < 4; ++ni) bf[ni] = *(const f16x8*)&Bs[(wc + ni * 16 + llo) * 32 + lhi * 8];
#pragma unroll
        for (int mi = 0; mi < 4; ++mi)
#pragma unroll
            for (int ni = 0; ni < 4; ++ni)
                acc[mi][ni] = MFMA16(af[mi], bf[ni], acc[mi][ni]);
        __syncthreads();
    }

    if (n0 < 2048) {
        // Q output, pre-scaled by CS so attention skips the per-score multiply
#pragma unroll
        for (int mi = 0; mi < 4; ++mi) {
            int m = m0 + wr + mi * 16 + lhi * 4;
#pragma unroll
            for (int ni = 0; ni < 4; ++ni) {
                int n = n0 + wc + ni * 16 + llo;
#pragma unroll
                for (int r = 0; r < 4; ++r)
                    Qb[(size_t)(m + r) * EMB + n] = (f16)(acc[mi][ni][r] * CS);
            }
        }
    } else if (n0 < 2560) {
#pragma unroll
        for (int mi = 0; mi < 4; ++mi) {
            int m = m0 + wr + mi * 16 + lhi * 4;
#pragma unroll
            for (int ni = 0; ni < 4; ++ni) {
                int n = n0 + wc + ni * 16 + llo - 2048;
#pragma unroll
                for (int r = 0; r < 4; ++r)
                    Kb[(size_t)(m + r) * 512 + n] = (f16)acc[mi][ni][r];
            }
        }
    } else {
#pragma unroll
        for (int mi = 0; mi < 4; ++mi) {
            int mb = m0 + wr + mi * 16 + lhi * 4;
#pragma unroll
            for (int ni = 0; ni < 4; ++ni) {
                int n = n0 + wc + ni * 16 + llo - 2560;
                f16x4 pv;
#pragma unroll
                for (int r = 0; r < 4; ++r) pv[r] = (f16)acc[mi][ni][r];
                *(f16x4*)&Vt[(size_t)n * SEQ + mb] = pv;
            }
        }
    }
}

// ---------------- flash attention (GQA), 8 waves x 16 q-rows, KV tile 64 ----------------
__global__ __launch_bounds__(512, 4) void attn_kernel(
    const f16* __restrict__ Qb, const f16* __restrict__ Kb, const f16* __restrict__ Vt,
    f16* __restrict__ AO)
{
    __shared__ f16 Ks[2][64 * 128];   // K-tile [t=64][k=128], chunk pos = logical ^ (row&7)
    __shared__ f16 Vs[2][128 * 64];   // V^T-tile [d=128][t=64], chunk pos = logical ^ (row&7)
    const int tid = threadIdx.x, lane = tid & 63, w = tid >> 6;
    const int llo = lane & 15, lhi = lane >> 4;
    const int h = blockIdx.y, hk = h >> 2;
    const int wm0 = blockIdx.x * 128 + w * 16;   // this wave's 16 q-rows
    const int hcol = h * HDIM;

    // Q fragments (Q pre-scaled by CS in qkv_gemm)
    f16x8 qf[4];
#pragma unroll
    for (int kk = 0; kk < 4; ++kk)
        qf[kk] = *(const f16x8*)&Qb[(size_t)(wm0 + llo) * EMB + hcol + kk * 32 + lhi * 8];

    // hoisted staging source pointers (advance by uniform t0 per tile)
    const f16* kgp[2];
    const f16* vgp[2];
#pragma unroll
    for (int i = 0; i < 2; ++i) {
        int c = tid + 512 * i;
        int row = c >> 4, cc = (c & 15) ^ (row & 7);
        kgp[i] = Kb + (size_t)row * 512 + hk * HDIM + cc * 8;
    }
#pragma unroll
    for (int i = 0; i < 2; ++i) {
        int c = tid + 512 * i;
        int row = c >> 3, cc = (c & 7) ^ (row & 7);
        vgp[i] = Vt + (size_t)(hk * HDIM + row) * SEQ + cc * 8;
    }

    float mrun = -3.0e38f;
    float lsum = 0.f;        // per-lane partial row-sum; reduced across lhi at the end
    f32x4 acc[8] = {};

    auto stage = [&](int buf, int t0) {
#pragma unroll
        for (int i = 0; i < 2; ++i)
            gload16(kgp[i] + (size_t)t0 * 512, &Ks[buf][(tid + 512 * i) * 8]);
#pragma unroll
        for (int i = 0; i < 2; ++i)
            gload16(vgp[i] + t0, &Vs[buf][(tid + 512 * i) * 8]);
    };

    stage(0, 0);
    __syncthreads();

    for (int tt = 0; tt < 64; ++tt) {
        int cur = tt & 1;
        if (tt < 63) stage(cur ^ 1, (tt + 1) * 64);  // prefetch overlaps compute

        // QK^T swapped: s = K_tile * Q -> lane holds q-row m=llo, t = 16*hh + lhi*4 + r
        f32x4 s[4] = {};
        __builtin_amdgcn_s_setprio(1);
#pragma unroll
        for (int kk = 0; kk < 4; ++kk) {
            f16x8 kf[4];
#pragma unroll
            for (int hh = 0; hh < 4; ++hh) {
                int row = llo + 16 * hh;
                int ccs = (kk * 4 + lhi) ^ (row & 7);
                kf[hh] = *(const f16x8*)&Ks[cur][row * 128 + ccs * 8];
            }
#pragma unroll
            for (int hh = 0; hh < 4; ++hh)
                s[hh] = MFMA16(kf[hh], qf[kk], s[hh]);
        }
        __builtin_amdgcn_s_setprio(0);

        // tile max (rows live at m=llo; reduce across lhi via permlane)
        float t = -3.0e38f;
#pragma unroll
        for (int hh = 0; hh < 4; ++hh)
#pragma unroll
            for (int r = 0; r < 4; ++r) t = fmaxf(t, s[hh][r]);
        float tm = red_max_lhi(t);

        // defer-max (T13): only rescale when the max grew by > 8 (log2 domain)
        if (__any(tm > mrun + 8.f)) {
            float mnew = fmaxf(mrun, tm);
            float alpha = __builtin_amdgcn_exp2f(mrun - mnew);
            mrun = mnew; lsum *= alpha;
            float ar[4];
#pragma unroll
            for (int r = 0; r < 4; ++r) ar[r] = __shfl(alpha, lhi * 4 + r, 64);
#pragma unroll
            for (int ni = 0; ni < 8; ++ni)
#pragma unroll
                for (int r = 0; r < 4; ++r) acc[ni][r] *= ar[r];
        }

        // exp (P bounded by 2^8), per-lane partial sum, pack P to fp16 dwords
        union F2U { f16x2 h; uint32_t u; };
        uint32_t Y[4][2];
        float ts = 0.f;
#pragma unroll
        for (int hh = 0; hh < 4; ++hh) {
#pragma unroll
            for (int r = 0; r < 4; ++r) { float p = __builtin_amdgcn_exp2f(s[hh][r] - mrun); s[hh][r] = p; ts += p; }
            F2U a, b;
            a.h[0] = (f16)s[hh][0]; a.h[1] = (f16)s[hh][1];
            b.h[0] = (f16)s[hh][2]; b.h[1] = (f16)s[hh][3];
            Y[hh][0] = a.u; Y[hh][1] = b.u;
        }
        lsum += ts;

        // gather P into A-frag [m=llo][t = 32c + 8*lhi + j] via permlane swaps
        f16x8 paf[2];
#pragma unroll
        for (int c = 0; c < 2; ++c) {
            union { f16x8 v; uint32_t u[4]; } pa;
#pragma unroll
            for (int jj = 0; jj < 2; ++jj) {
                uint32_t xa = Y[2 * c][jj], xb = Y[2 * c + 1][jj];
                swap32p(xa, xb);
                swap16p(xa, xb);
                pa.u[jj] = xa; pa.u[2 + jj] = xb;
            }
            paf[c] = pa.v;
        }

        // PV: out[m][d] += P * V  (V^T rows are t-contiguous; pos swizzled by d&7)
        __builtin_amdgcn_s_setprio(1);
#pragma unroll
        for (int c = 0; c < 2; ++c)
#pragma unroll
            for (int ni = 0; ni < 8; ++ni) {
                int d = ni * 16 + llo;
                f16x8 vf = *(const f16x8*)&Vs[cur][d * 64 + (((4 * c + lhi) ^ (d & 7)) * 8)];
                acc[ni] = MFMA16(paf[c], vf, acc[ni]);
            }
        __builtin_amdgcn_s_setprio(0);

        __syncthreads();  // drains prefetch (vmcnt 0) + barrier: next buffer ready
    }

    // finalize: divide by row sums, store merged-head fp16 [4096][2048]
    float linv = 1.0f / red_sum_lhi(lsum);
    float lr[4];
#pragma unroll
    for (int r = 0; r < 4; ++r) lr[r] = __shfl(linv, lhi * 4 + r, 64);
#pragma unroll
    for (int ni = 0; ni < 8; ++ni) {
        int n = hcol + ni * 16 + llo;
#pragma unroll
        for (int r = 0; r < 4; ++r)
            AO[(size_t)(wm0 + lhi * 4 + r) * EMB + n] = (f16)(acc[ni][r] * lr[r]);
    }
}

// ---------------- output projection: out = AO @ Wo^T, fp32 out ----------------
__global__ __launch_bounds__(256) void o_gemm(
    const f16* __restrict__ A, const f16* __restrict__ Bw,
    float* __restrict__ Co)
{
    __shared__ f16 As[128 * 32];
    __shared__ f16 Bs[128 * 32];
    const int tid = threadIdx.x;
    const int lane = tid & 63;
    const int w = tid >> 6;
    const int llo = lane & 15, lhi = lane >> 4;
    const int m0 = blockIdx.y * 128;
    const int n0 = blockIdx.x * 128;
    const int wr = (w >> 1) * 64, wc = (w & 1) * 64;

    f32x4 acc[4][4] = {};

    for (int k0 = 0; k0 < EMB; k0 += 32) {
#pragma unroll
        for (int i = 0; i < 2; ++i) {
            int c = tid + 256 * i;
            gload16(A + (size_t)(m0 + (c >> 2)) * EMB + k0 + (c & 3) * 8, &As[c * 8]);
        }
#pragma unroll
        for (int i = 0; i < 2; ++i) {
            int c = tid + 256 * i;
            gload16(Bw + (size_t)(n0 + (c >> 2)) * EMB + k0 + (c & 3) * 8, &Bs[c * 8]);
        }
        __syncthreads();
        f16x8 af[4], bf[4];
#pragma unroll
        for (int mi = 0; mi < 4; ++mi) af[mi] = *(const f16x8*)&As[(wr + mi * 16 + llo) * 32 + lhi * 8];
#pragma unroll
        for (int ni = 0; ni < 4; ++ni) bf[ni] = *(const f16x8*)&Bs[(wc + ni * 16 + llo) * 32 + lhi * 8];
#pragma unroll
        for (int mi = 0; mi < 4; ++mi)
#pragma unroll
            for (int ni = 0; ni < 4; ++ni)
                acc[mi][ni] = MFMA16(af[mi], bf[ni], acc[mi][ni]);
        __syncthreads();
    }

#pragma unroll
    for (int mi = 0; mi < 4; ++mi) {
        int m = m0 + wr + mi * 16 + lhi * 4;
#pragma unroll
        for (int ni = 0; ni < 4; ++ni) {
            int n = n0 + wc + ni * 16 + llo;
#pragma unroll
            for (int r = 0; r < 4; ++r)
                Co[(size_t)(m + r) * EMB + n] = acc[mi][ni][r];
        }
    }
}

extern "C" void kernel_launch(void* const* d_in, const int* in_sizes, int n_in,
                              void* d_out, int out_size, void* d_ws, size_t ws_size,
                              hipStream_t stream) {
    const float* x  = (const float*)d_in[0];
    const float* wq = (const float*)d_in[1];
    const float* wk = (const float*)d_in[2];
    const float* wv = (const float*)d_in[3];
    const float* wo = (const float*)d_in[4];
    f16* ws = (f16*)d_ws;

    f16* Xh   = ws + OFF_XH;     // also AO after attention
    f16* Wcat = ws + OFF_WCAT;
    f16* Wo16 = ws + OFF_WO;
    f16* Qb   = ws + OFF_Q;
    f16* Kb   = ws + OFF_K;
    f16* Vt   = ws + OFF_VT;

    cvt_kernel<<<18432, 256, 0, stream>>>(x, wq, wk, wv, wo, ws);
    qkv_gemm<<<dim3(24, 32), 256, 0, stream>>>(Xh, Wcat, Qb, Kb, Vt);
    attn_kernel<<<dim3(32, 16), 512, 0, stream>>>(Qb, Kb, Vt, Xh /*AO*/);
    o_gemm<<<dim3(16, 32), 256, 0, stream>>>(Xh /*AO*/, Wo16, (float*)d_out);
}